// Round 4
// baseline (211.721 us; speedup 1.0000x reference)
//
#include <hip/hip_runtime.h>

#define B_ 256
#define N_ 64
#define T_ 60
#define D_ 128
#define H_ 128

typedef __attribute__((ext_vector_type(8))) short short8;
typedef __attribute__((ext_vector_type(4))) float f32x4;

__device__ __forceinline__ unsigned short f2bf(float f) {
  unsigned int u = __builtin_bit_cast(unsigned int, f);
  u = u + 0x7FFFu + ((u >> 16) & 1u);   // round-to-nearest-even
  return (unsigned short)(u >> 16);
}

__device__ __forceinline__ float tanh_fast(float x) {
  float e = __builtin_amdgcn_exp2f(x * 2.885390081777927f);  // exp(2x)
  return 1.0f - 2.0f * __builtin_amdgcn_rcpf(e + 1.0f);
}

// Pack W (K=128 x N=128, row-major [k][n]) into bf16 B-fragment order:
// [kt(4)][nt(8)][lane(64)][elem(8)], value = W[kt*32 + 8*(l>>4) + i][nt*16 + (l&15)]
__global__ __launch_bounds__(256) void prep_weights(
    const float* __restrict__ sg_w1, const float* __restrict__ tg_w1,
    unsigned short* __restrict__ wfrag) {
  int tid = blockIdx.x * 256 + threadIdx.x;   // 0..4095
  if (tid >= 2 * 4 * 8 * 64) return;
  int l  = tid & 63;
  int nt = (tid >> 6) & 7;
  int kt = (tid >> 9) & 3;
  int m  = tid >> 11;
  const float* W = m ? tg_w1 : sg_w1;
  int n  = nt * 16 + (l & 15);
  int k0 = kt * 32 + 8 * (l >> 4);
  unsigned short* dst = wfrag + (size_t)tid * 8;
#pragma unroll
  for (int i = 0; i < 8; ++i) dst[i] = f2bf(W[(k0 + i) * H_ + n]);
}

// One block per (b,t). Stage bf16 tile in LDS for MFMA; pool by re-reading
// x from global (L2-hot). Two barriers total; no softmax max-pass.
__global__ __launch_bounds__(256, 4) void spatial_kernel(
    const float* __restrict__ x,
    const short8* __restrict__ wfrag,     // [4][8][64] fragments of sg_w1
    const float* __restrict__ b1,
    const float* __restrict__ w2,
    float* __restrict__ pooled) {
  // bf16 tile: row n at byte n*272 (256B data + 16B pad -> 2-way/conflict-free)
  __shared__ __align__(16) char xs16[64 * 272];
  __shared__ float gpart[64];

  const int tid = threadIdx.x;
  const int bid = blockIdx.x;
  const int b = bid / T_;
  const int t = bid - b * T_;

  const float* xb = x + (size_t)b * (N_ * T_ * D_) + (size_t)t * D_;

  const int cg  = tid >> 3;   // 0..31  (column group of 4 floats)
  const int sub = tid & 7;    // 0..7   (row sub-slot)
  const int l   = tid & 63;
  const int w   = tid >> 6;
  const int lg  = l >> 4;
  const int lr  = l & 15;

  // ---- stage: load 8 float4, convert to bf16, ds_write 8B each ----
#pragma unroll
  for (int r = 0; r < 8; ++r) {
    const int n = sub + 8 * r;
    float4 v = *(const float4*)(xb + (size_t)n * (T_ * D_) + 4 * cg);
    unsigned lo = ((unsigned)f2bf(v.y) << 16) | f2bf(v.x);
    unsigned hi = ((unsigned)f2bf(v.w) << 16) | f2bf(v.z);
    *(uint2*)(xs16 + n * 272 + cg * 8) = make_uint2(lo, hi);
  }
  __syncthreads();

  float b1v[8], w2v[8];
#pragma unroll
  for (int nt = 0; nt < 8; ++nt) {
    b1v[nt] = b1[nt * 16 + lr];
    w2v[nt] = w2[nt * 16 + lr];
  }

  // ---- MFMA: h = x @ W1; wave w owns nodes 16w..16w+15, all 128 cols ----
  f32x4 acc[8];
#pragma unroll
  for (int nt = 0; nt < 8; ++nt) acc[nt] = (f32x4)(0.0f);

  const int row = 16 * w + lr;
  const char* abase = xs16 + row * 272 + lg * 16;
#pragma unroll
  for (int kt = 0; kt < 4; ++kt) {
    short8 af = *(const short8*)(abase + kt * 64);
#pragma unroll
    for (int nt = 0; nt < 8; ++nt) {
      short8 bf = wfrag[(kt * 8 + nt) * 64 + l];
      acc[nt] = __builtin_amdgcn_mfma_f32_16x16x32_bf16(af, bf, acc[nt], 0, 0, 0);
    }
  }

  // ---- gate[node] = sum_m tanh(h + b1) * w2 ; node = 16w + 4lg + j ----
#pragma unroll
  for (int j = 0; j < 4; ++j) {
    float s = 0.f;
#pragma unroll
    for (int nt = 0; nt < 8; ++nt) {
      float h = acc[nt][j] + b1v[nt];
      s += tanh_fast(h) * w2v[nt];
    }
    s += __shfl_xor(s, 1);
    s += __shfl_xor(s, 2);
    s += __shfl_xor(s, 4);
    s += __shfl_xor(s, 8);
    if (lr == 0) gpart[16 * w + 4 * lg + j] = s;
  }
  __syncthreads();

  // ---- softmax over 64 nodes, no max shift (|gate| <~ 11, exp safe) ----
  float p = __builtin_amdgcn_exp2f(gpart[l] * 1.4426950408889634f);
  float sm = p;
  sm += __shfl_xor(sm, 32);
  sm += __shfl_xor(sm, 16);
  sm += __shfl_xor(sm, 8);
  sm += __shfl_xor(sm, 4);
  sm += __shfl_xor(sm, 2);
  sm += __shfl_xor(sm, 1);
  const float alpha = p * __builtin_amdgcn_rcpf(sm);  // alpha for node == lane

  // ---- pool: re-read x from global (L2-hot), weight, reduce over sub ----
  const float* xb2 = xb;
  asm volatile("" : "+r"(xb2));   // prevent CSE with staging loads
  f32x4 q = (f32x4)(0.0f);
#pragma unroll
  for (int r = 0; r < 8; ++r) {
    const int n = sub + 8 * r;
    const float av = __shfl(alpha, n);
    f32x4 v = *(const f32x4*)(xb2 + (size_t)n * (T_ * D_) + 4 * cg);
    q += av * v;
  }
#pragma unroll
  for (int m = 1; m <= 4; m <<= 1) {
    q[0] += __shfl_xor(q[0], m);
    q[1] += __shfl_xor(q[1], m);
    q[2] += __shfl_xor(q[2], m);
    q[3] += __shfl_xor(q[3], m);
  }
  if (sub == 0)
    *(f32x4*)(pooled + ((size_t)b * T_ + t) * D_ + 4 * cg) = q;
}

__global__ __launch_bounds__(256) void temporal_kernel(
    const float* __restrict__ pooled,
    const short8* __restrict__ wfrag,     // fragments of tg_w1
    const float* __restrict__ b1,
    const float* __restrict__ w2,
    float* __restrict__ out) {
  __shared__ float xs[64][132];
  __shared__ float score_lds[64];
  __shared__ float tw_lds[64];
  __shared__ float pp[2][128];

  const int tid = threadIdx.x;
  const int b = blockIdx.x;

  const float* pb = pooled + (size_t)b * T_ * D_;
#pragma unroll
  for (int it = 0; it < 8; ++it) {
    int q = it * 256 + tid;
    int n = q >> 5;
    int c4 = (q & 31) << 2;
    float4 v = {0.f, 0.f, 0.f, 0.f};
    if (n < T_) v = *(const float4*)(pb + n * D_ + c4);
    *(float4*)(&xs[n][c4]) = v;   // rows 60..63 zero-padded
  }
  __syncthreads();

  const int l = tid & 63;
  const int w = tid >> 6;
  const int lg = l >> 4;
  const int lr = l & 15;

  float b1v[8], w2v[8];
#pragma unroll
  for (int nt = 0; nt < 8; ++nt) {
    b1v[nt] = b1[nt * 16 + lr];
    w2v[nt] = w2[nt * 16 + lr];
  }

  f32x4 acc[8];
#pragma unroll
  for (int nt = 0; nt < 8; ++nt) acc[nt] = (f32x4)(0.0f);

  const int row = 16 * w + lr;
#pragma unroll
  for (int kt = 0; kt < 4; ++kt) {
    const int k0 = kt * 32 + 8 * lg;
    float4 a0 = *(const float4*)(&xs[row][k0]);
    float4 a1 = *(const float4*)(&xs[row][k0 + 4]);
    short8 af;
    af[0] = (short)f2bf(a0.x); af[1] = (short)f2bf(a0.y);
    af[2] = (short)f2bf(a0.z); af[3] = (short)f2bf(a0.w);
    af[4] = (short)f2bf(a1.x); af[5] = (short)f2bf(a1.y);
    af[6] = (short)f2bf(a1.z); af[7] = (short)f2bf(a1.w);
#pragma unroll
    for (int nt = 0; nt < 8; ++nt) {
      short8 bf = wfrag[(kt * 8 + nt) * 64 + l];
      acc[nt] = __builtin_amdgcn_mfma_f32_16x16x32_bf16(af, bf, acc[nt], 0, 0, 0);
    }
  }

#pragma unroll
  for (int j = 0; j < 4; ++j) {
    float s = 0.f;
#pragma unroll
    for (int nt = 0; nt < 8; ++nt) {
      float h = acc[nt][j] + b1v[nt];
      s += tanh_fast(h) * w2v[nt];
    }
    s += __shfl_xor(s, 1);
    s += __shfl_xor(s, 2);
    s += __shfl_xor(s, 4);
    s += __shfl_xor(s, 8);
    if (lr == 0) score_lds[16 * w + 4 * lg + j] = s;
  }
  __syncthreads();

  // masked softmax over T=60 (no max shift; scores bounded)
  float p = (l < T_) ? __builtin_amdgcn_exp2f(score_lds[l] * 1.4426950408889634f) : 0.f;
  float sm = p;
  sm += __shfl_xor(sm, 32);
  sm += __shfl_xor(sm, 16);
  sm += __shfl_xor(sm, 8);
  sm += __shfl_xor(sm, 4);
  sm += __shfl_xor(sm, 2);
  sm += __shfl_xor(sm, 1);
  float tw = p / sm;
  if (w == 0) {
    tw_lds[l] = tw;
    if (l < T_) out[B_ * D_ + b * T_ + l] = tw;   // tw output
  }
  __syncthreads();

  const int c = tid & 127;
  const int hh = tid >> 7;
  float s = 0.f;
#pragma unroll
  for (int i = 0; i < 30; ++i) {
    int tt = 30 * hh + i;
    s += tw_lds[tt] * xs[tt][c];
  }
  pp[hh][c] = s;
  __syncthreads();
  if (tid < 128) out[(size_t)b * D_ + tid] = pp[0][tid] + pp[1][tid];
}

extern "C" void kernel_launch(void* const* d_in, const int* in_sizes, int n_in,
                              void* d_out, int out_size, void* d_ws, size_t ws_size,
                              hipStream_t stream) {
  const float* x     = (const float*)d_in[0];
  const float* sg_w1 = (const float*)d_in[1];
  const float* sg_b1 = (const float*)d_in[2];
  const float* sg_w2 = (const float*)d_in[3];
  const float* tg_w1 = (const float*)d_in[5];
  const float* tg_b1 = (const float*)d_in[6];
  const float* tg_w2 = (const float*)d_in[7];
  float* out = (float*)d_out;

  unsigned short* wfrag = (unsigned short*)d_ws;            // 2 * 2048 * 8 ushorts = 64 KB
  float* pooled = (float*)((char*)d_ws + 65536);            // B*T*D f32 = 7.86 MB

  prep_weights<<<16, 256, 0, stream>>>(sg_w1, tg_w1, wfrag);
  spatial_kernel<<<B_ * T_, 256, 0, stream>>>(
      x, (const short8*)wfrag, sg_b1, sg_w2, pooled);
  temporal_kernel<<<B_, 256, 0, stream>>>(
      pooled, (const short8*)(wfrag + 16384), tg_b1, tg_w2, out);
}

// Round 5
// 157.139 us; speedup vs baseline: 1.3473x; 1.3473x over previous
//
#include <hip/hip_runtime.h>

#define B_ 256
#define N_ 64
#define T_ 60
#define D_ 128
#define H_ 128

typedef __attribute__((ext_vector_type(8))) short short8;
typedef __attribute__((ext_vector_type(4))) float f32x4;

__device__ __forceinline__ unsigned short f2bf(float f) {
  unsigned int u = __builtin_bit_cast(unsigned int, f);
  u = u + 0x7FFFu + ((u >> 16) & 1u);   // round-to-nearest-even
  return (unsigned short)(u >> 16);
}

__device__ __forceinline__ float tanh_fast(float x) {
  float e = __builtin_amdgcn_exp2f(x * 2.885390081777927f);  // exp(2x)
  return 1.0f - 2.0f * __builtin_amdgcn_rcpf(e + 1.0f);
}

#define GLOAD_LDS16(gp, lp)                                        \
  __builtin_amdgcn_global_load_lds(                                \
      (const __attribute__((address_space(1))) void*)(gp),         \
      (__attribute__((address_space(3))) void*)(lp), 16, 0, 0)

// Pack W (K=128 x N=128, row-major [k][n]) into bf16 B-fragment order:
// [kt(4)][nt(8)][lane(64)][elem(8)], value = W[kt*32 + 8*(l>>4) + i][nt*16 + (l&15)]
__global__ __launch_bounds__(256) void prep_weights(
    const float* __restrict__ sg_w1, const float* __restrict__ tg_w1,
    unsigned short* __restrict__ wfrag) {
  int tid = blockIdx.x * 256 + threadIdx.x;   // 0..4095
  if (tid >= 2 * 4 * 8 * 64) return;
  int l  = tid & 63;
  int nt = (tid >> 6) & 7;
  int kt = (tid >> 9) & 3;
  int m  = tid >> 11;
  const float* W = m ? tg_w1 : sg_w1;
  int n  = nt * 16 + (l & 15);
  int k0 = kt * 32 + 8 * (l >> 4);
  unsigned short* dst = wfrag + (size_t)tid * 8;
#pragma unroll
  for (int i = 0; i < 8; ++i) dst[i] = f2bf(W[(k0 + i) * H_ + n]);
}

// One block per (b,t). f32 x-tile staged via global_load_lds into linear LDS
// with source-side slot XOR swizzle (slot ^= row&7). Waves split the gate MLP
// 2x2 (row-half x col-half) so W-fragment L2 traffic is 64KB/block not 128KB.
// Pool in f32 from the same LDS tile. 3 barriers. No softmax max-pass.
__global__ __launch_bounds__(256, 4) void spatial_kernel(
    const float* __restrict__ x,
    const short8* __restrict__ wfrag,     // [4][8][64] fragments of sg_w1
    const float* __restrict__ b1,
    const float* __restrict__ w2,
    float* __restrict__ pooled) {
  __shared__ __align__(16) float xs[64 * 128];   // linear, swizzled content
  __shared__ float gpart[2][64];
  __shared__ float pp[2][128];

  const int tid = threadIdx.x;
  const int bid = blockIdx.x;
  const int b = bid / T_;
  const int t = bid - b * T_;

  const char* xbc = (const char*)(x + (size_t)b * (N_ * T_ * D_) + (size_t)t * D_);

  // ---- stage: 8 x global_load_lds(16B) per thread, swizzled source ----
#pragma unroll
  for (int it = 0; it < 8; ++it) {
    int q = it * 256 + tid;
    int n = q >> 5;
    unsigned soff = (unsigned)n * (T_ * D_ * 4) + ((((q & 31) * 16)) ^ ((n & 7) << 4));
    GLOAD_LDS16(xbc + soff, (char*)xs + it * 4096 + (tid & 192) * 16);
  }
  __syncthreads();   // drains vmcnt(0): tile resident

  const int l  = tid & 63;
  const int w  = tid >> 6;
  const int lg = l >> 4;
  const int lr = l & 15;
  const int wr = w >> 1;   // row half: nodes [32*wr, 32*wr+32)
  const int wc = w & 1;    // col half: H cols [64*wc, 64*wc+64)

  float b1v[4], w2v[4];
#pragma unroll
  for (int ntl = 0; ntl < 4; ++ntl) {
    b1v[ntl] = b1[wc * 64 + ntl * 16 + lr];
    w2v[ntl] = w2[wc * 64 + ntl * 16 + lr];
  }

  // ---- MFMA: h = x @ W1 for this wave's (row-half x col-half) ----
  f32x4 acc[2][4];
#pragma unroll
  for (int mt = 0; mt < 2; ++mt)
#pragma unroll
    for (int ntl = 0; ntl < 4; ++ntl) acc[mt][ntl] = (f32x4)(0.0f);

#pragma unroll
  for (int kt = 0; kt < 4; ++kt) {
#pragma unroll
    for (int mt = 0; mt < 2; ++mt) {
      const int row = 32 * wr + 16 * mt + lr;
      const int byte0 = row * 512 + (((kt * 8 + 2 * lg) * 16) ^ ((row & 7) << 4));
      f32x4 a0 = *(const f32x4*)((const char*)xs + byte0);
      f32x4 a1 = *(const f32x4*)((const char*)xs + (byte0 ^ 16));
      short8 af;
      af[0] = (short)f2bf(a0[0]); af[1] = (short)f2bf(a0[1]);
      af[2] = (short)f2bf(a0[2]); af[3] = (short)f2bf(a0[3]);
      af[4] = (short)f2bf(a1[0]); af[5] = (short)f2bf(a1[1]);
      af[6] = (short)f2bf(a1[2]); af[7] = (short)f2bf(a1[3]);
#pragma unroll
      for (int ntl = 0; ntl < 4; ++ntl) {
        short8 bf = wfrag[(kt * 8 + wc * 4 + ntl) * 64 + l];   // streamed from L2
        acc[mt][ntl] = __builtin_amdgcn_mfma_f32_16x16x32_bf16(af, bf, acc[mt][ntl], 0, 0, 0);
      }
    }
  }

  // ---- gate partials over this wave's 64 cols; node = 32wr+16mt+4lg+j ----
#pragma unroll
  for (int mt = 0; mt < 2; ++mt) {
#pragma unroll
    for (int j = 0; j < 4; ++j) {
      float s = 0.f;
#pragma unroll
      for (int ntl = 0; ntl < 4; ++ntl) {
        float h = acc[mt][ntl][j] + b1v[ntl];
        s += tanh_fast(h) * w2v[ntl];
      }
      s += __shfl_xor(s, 1);
      s += __shfl_xor(s, 2);
      s += __shfl_xor(s, 4);
      s += __shfl_xor(s, 8);
      if (lr == 0) gpart[wc][32 * wr + 16 * mt + 4 * lg + j] = s;
    }
  }
  __syncthreads();

  // ---- softmax over 64 nodes, no max shift (|gate| bounded by sum|w2|) ----
  float g = gpart[0][l] + gpart[1][l];
  float p = __builtin_amdgcn_exp2f(g * 1.4426950408889634f);
  float sm = p;
  sm += __shfl_xor(sm, 32);
  sm += __shfl_xor(sm, 16);
  sm += __shfl_xor(sm, 8);
  sm += __shfl_xor(sm, 4);
  sm += __shfl_xor(sm, 2);
  sm += __shfl_xor(sm, 1);
  const float alpha = p * __builtin_amdgcn_rcpf(sm);   // alpha for node == lane

  // ---- pool from LDS (f32): col-parallel, alpha via shfl ----
  {
    const int c  = tid & 127;
    const int hh = tid >> 7;        // rows [32*hh, 32*hh+32)
    const unsigned cbase = 4u * c;  // byte = (cbase ^ ((n&7)<<4)) + n*512
    float s = 0.f;
#pragma unroll
    for (int i = 0; i < 32; ++i) {
      const int n = 32 * hh + i;
      const float av = __shfl(alpha, n);
      const float xv = *(const float*)((const char*)xs + ((cbase ^ ((unsigned)(n & 7) << 4)) + (unsigned)n * 512));
      s += av * xv;
    }
    pp[hh][c] = s;
  }
  __syncthreads();

  if (tid < 128)
    pooled[((size_t)b * T_ + t) * D_ + tid] = pp[0][tid] + pp[1][tid];
}

__global__ __launch_bounds__(256) void temporal_kernel(
    const float* __restrict__ pooled,
    const short8* __restrict__ wfrag,     // fragments of tg_w1
    const float* __restrict__ b1,
    const float* __restrict__ w2,
    float* __restrict__ out) {
  __shared__ float xs[64][132];
  __shared__ float score_lds[64];
  __shared__ float tw_lds[64];
  __shared__ float pp[2][128];

  const int tid = threadIdx.x;
  const int b = blockIdx.x;

  const float* pb = pooled + (size_t)b * T_ * D_;
#pragma unroll
  for (int it = 0; it < 8; ++it) {
    int q = it * 256 + tid;
    int n = q >> 5;
    int c4 = (q & 31) << 2;
    float4 v = {0.f, 0.f, 0.f, 0.f};
    if (n < T_) v = *(const float4*)(pb + n * D_ + c4);
    *(float4*)(&xs[n][c4]) = v;   // rows 60..63 zero-padded
  }
  __syncthreads();

  const int l = tid & 63;
  const int w = tid >> 6;
  const int lg = l >> 4;
  const int lr = l & 15;

  float b1v[8], w2v[8];
#pragma unroll
  for (int nt = 0; nt < 8; ++nt) {
    b1v[nt] = b1[nt * 16 + lr];
    w2v[nt] = w2[nt * 16 + lr];
  }

  f32x4 acc[8];
#pragma unroll
  for (int nt = 0; nt < 8; ++nt) acc[nt] = (f32x4)(0.0f);

  const int row = 16 * w + lr;
#pragma unroll
  for (int kt = 0; kt < 4; ++kt) {
    const int k0 = kt * 32 + 8 * lg;
    float4 a0 = *(const float4*)(&xs[row][k0]);
    float4 a1 = *(const float4*)(&xs[row][k0 + 4]);
    short8 af;
    af[0] = (short)f2bf(a0.x); af[1] = (short)f2bf(a0.y);
    af[2] = (short)f2bf(a0.z); af[3] = (short)f2bf(a0.w);
    af[4] = (short)f2bf(a1.x); af[5] = (short)f2bf(a1.y);
    af[6] = (short)f2bf(a1.z); af[7] = (short)f2bf(a1.w);
#pragma unroll
    for (int nt = 0; nt < 8; ++nt) {
      short8 bf = wfrag[(kt * 8 + nt) * 64 + l];
      acc[nt] = __builtin_amdgcn_mfma_f32_16x16x32_bf16(af, bf, acc[nt], 0, 0, 0);
    }
  }

#pragma unroll
  for (int j = 0; j < 4; ++j) {
    float s = 0.f;
#pragma unroll
    for (int nt = 0; nt < 8; ++nt) {
      float h = acc[nt][j] + b1v[nt];
      s += tanh_fast(h) * w2v[nt];
    }
    s += __shfl_xor(s, 1);
    s += __shfl_xor(s, 2);
    s += __shfl_xor(s, 4);
    s += __shfl_xor(s, 8);
    if (lr == 0) score_lds[16 * w + 4 * lg + j] = s;
  }
  __syncthreads();

  // masked softmax over T=60 (no max shift; scores bounded)
  float p = (l < T_) ? __builtin_amdgcn_exp2f(score_lds[l] * 1.4426950408889634f) : 0.f;
  float sm = p;
  sm += __shfl_xor(sm, 32);
  sm += __shfl_xor(sm, 16);
  sm += __shfl_xor(sm, 8);
  sm += __shfl_xor(sm, 4);
  sm += __shfl_xor(sm, 2);
  sm += __shfl_xor(sm, 1);
  float tw = p / sm;
  if (w == 0) {
    tw_lds[l] = tw;
    if (l < T_) out[B_ * D_ + b * T_ + l] = tw;   // tw output
  }
  __syncthreads();

  const int c = tid & 127;
  const int hh = tid >> 7;
  float s = 0.f;
#pragma unroll
  for (int i = 0; i < 30; ++i) {
    int tt = 30 * hh + i;
    s += tw_lds[tt] * xs[tt][c];
  }
  pp[hh][c] = s;
  __syncthreads();
  if (tid < 128) out[(size_t)b * D_ + tid] = pp[0][tid] + pp[1][tid];
}

extern "C" void kernel_launch(void* const* d_in, const int* in_sizes, int n_in,
                              void* d_out, int out_size, void* d_ws, size_t ws_size,
                              hipStream_t stream) {
  const float* x     = (const float*)d_in[0];
  const float* sg_w1 = (const float*)d_in[1];
  const float* sg_b1 = (const float*)d_in[2];
  const float* sg_w2 = (const float*)d_in[3];
  const float* tg_w1 = (const float*)d_in[5];
  const float* tg_b1 = (const float*)d_in[6];
  const float* tg_w2 = (const float*)d_in[7];
  float* out = (float*)d_out;

  unsigned short* wfrag = (unsigned short*)d_ws;            // 2 * 2048 * 8 ushorts = 64 KB
  float* pooled = (float*)((char*)d_ws + 65536);            // B*T*D f32 = 7.86 MB

  prep_weights<<<16, 256, 0, stream>>>(sg_w1, tg_w1, wfrag);
  spatial_kernel<<<B_ * T_, 256, 0, stream>>>(
      x, (const short8*)wfrag, sg_b1, sg_w2, pooled);
  temporal_kernel<<<B_, 256, 0, stream>>>(
      pooled, (const short8*)(wfrag + 16384), tg_b1, tg_w2, out);
}

// Round 6
// 154.140 us; speedup vs baseline: 1.3736x; 1.0195x over previous
//
#include <hip/hip_runtime.h>

#define B_ 256
#define N_ 64
#define T_ 60
#define D_ 128
#define H_ 128

typedef __attribute__((ext_vector_type(8))) short short8;
typedef __attribute__((ext_vector_type(4))) float f32x4;

__device__ __forceinline__ unsigned short f2bf(float f) {
  unsigned int u = __builtin_bit_cast(unsigned int, f);
  u = u + 0x7FFFu + ((u >> 16) & 1u);   // round-to-nearest-even
  return (unsigned short)(u >> 16);
}

__device__ __forceinline__ float tanh_fast(float x) {
  float e = __builtin_amdgcn_exp2f(x * 2.885390081777927f);  // exp(2x)
  return 1.0f - 2.0f * __builtin_amdgcn_rcpf(e + 1.0f);
}

// Pack W (K=128 x N=128, row-major [k][n]) into bf16 B-fragment order:
// [kt(4)][nt(8)][lane(64)][elem(8)], value = W[kt*32 + 8*(l>>4) + i][nt*16 + (l&15)]
__global__ __launch_bounds__(256) void prep_weights(
    const float* __restrict__ sg_w1, const float* __restrict__ tg_w1,
    unsigned short* __restrict__ wfrag) {
  int tid = blockIdx.x * 256 + threadIdx.x;   // 0..4095
  if (tid >= 2 * 4 * 8 * 64) return;
  int l  = tid & 63;
  int nt = (tid >> 6) & 7;
  int kt = (tid >> 9) & 3;
  int m  = tid >> 11;
  const float* W = m ? tg_w1 : sg_w1;
  int n  = nt * 16 + (l & 15);
  int k0 = kt * 32 + 8 * (l >> 4);
  unsigned short* dst = wfrag + (size_t)tid * 8;
#pragma unroll
  for (int i = 0; i < 8; ++i) dst[i] = f2bf(W[(k0 + i) * H_ + n]);
}

// One block per (b,t). Stage: global->regs (kept live), bf16 copy to LDS for
// MFMA. Pool directly from the f32 staging registers (no LDS/global re-read).
// 2 barriers. No softmax max-pass. ~18KB LDS, target VGPR<=102 (5 blocks/CU).
__global__ __launch_bounds__(256, 4) void spatial_kernel(
    const float* __restrict__ x,
    const short8* __restrict__ wfrag,     // [4][8][64] fragments of sg_w1
    const float* __restrict__ b1,
    const float* __restrict__ w2,
    float* __restrict__ pooled) {
  __shared__ __align__(16) char xs16[64 * 272];   // bf16 tile, 272B row stride
  __shared__ float gpart[2][64];

  const int tid = threadIdx.x;
  const int bid = blockIdx.x;
  const int b = bid / T_;
  const int t = bid - b * T_;

  const float* xb = x + (size_t)b * (N_ * T_ * D_) + (size_t)t * D_;

  const int cg  = tid >> 3;   // 0..31  column group (4 floats)
  const int sub = tid & 7;    // 0..7   row sub-slot

  // ---- stage: 8 float4 -> regs (live until pool), bf16 copy -> LDS ----
  float4 px[8];
#pragma unroll
  for (int r = 0; r < 8; ++r) {
    const int n = sub + 8 * r;
    px[r] = *(const float4*)(xb + (size_t)n * (T_ * D_) + 4 * cg);
  }
#pragma unroll
  for (int r = 0; r < 8; ++r) {
    const int n = sub + 8 * r;
    unsigned lo = ((unsigned)f2bf(px[r].y) << 16) | f2bf(px[r].x);
    unsigned hi = ((unsigned)f2bf(px[r].w) << 16) | f2bf(px[r].z);
    *(uint2*)(xs16 + n * 272 + cg * 8) = make_uint2(lo, hi);
  }
  __syncthreads();

  const int l  = tid & 63;
  const int w  = tid >> 6;
  const int lg = l >> 4;
  const int lr = l & 15;
  const int wr = w >> 1;   // row half: nodes [32*wr, 32*wr+32)
  const int wc = w & 1;    // col half: H cols [64*wc, 64*wc+64)

  float b1v[4], w2v[4];
#pragma unroll
  for (int ntl = 0; ntl < 4; ++ntl) {
    b1v[ntl] = b1[wc * 64 + ntl * 16 + lr];
    w2v[ntl] = w2[wc * 64 + ntl * 16 + lr];
  }

  // ---- MFMA: h = x @ W1 for this wave's (row-half x col-half) ----
  f32x4 acc[2][4];
#pragma unroll
  for (int mt = 0; mt < 2; ++mt)
#pragma unroll
    for (int ntl = 0; ntl < 4; ++ntl) acc[mt][ntl] = (f32x4)(0.0f);

#pragma unroll
  for (int kt = 0; kt < 4; ++kt) {
#pragma unroll
    for (int mt = 0; mt < 2; ++mt) {
      const int row = 32 * wr + 16 * mt + lr;
      short8 af = *(const short8*)(xs16 + row * 272 + kt * 64 + lg * 16);
#pragma unroll
      for (int ntl = 0; ntl < 4; ++ntl) {
        short8 bf = wfrag[(kt * 8 + wc * 4 + ntl) * 64 + l];   // streamed from L2
        acc[mt][ntl] = __builtin_amdgcn_mfma_f32_16x16x32_bf16(af, bf, acc[mt][ntl], 0, 0, 0);
      }
    }
  }

  // ---- gate partials; node = 32wr + 16mt + 4lg + j ----
#pragma unroll
  for (int mt = 0; mt < 2; ++mt) {
#pragma unroll
    for (int j = 0; j < 4; ++j) {
      float s = 0.f;
#pragma unroll
      for (int ntl = 0; ntl < 4; ++ntl) {
        float h = acc[mt][ntl][j] + b1v[ntl];
        s += tanh_fast(h) * w2v[ntl];
      }
      s += __shfl_xor(s, 1);
      s += __shfl_xor(s, 2);
      s += __shfl_xor(s, 4);
      s += __shfl_xor(s, 8);
      if (lr == 0) gpart[wc][32 * wr + 16 * mt + 4 * lg + j] = s;
    }
  }
  __syncthreads();

  // ---- softmax over 64 nodes, no max shift (|gate| bounded by sum|w2|) ----
  float g = gpart[0][l] + gpart[1][l];
  float p = __builtin_amdgcn_exp2f(g * 1.4426950408889634f);
  float sm = p;
  sm += __shfl_xor(sm, 32);
  sm += __shfl_xor(sm, 16);
  sm += __shfl_xor(sm, 8);
  sm += __shfl_xor(sm, 4);
  sm += __shfl_xor(sm, 2);
  sm += __shfl_xor(sm, 1);
  const float alpha = p * __builtin_amdgcn_rcpf(sm);   // alpha for node == lane

  // ---- pool from the f32 staging registers; reduce across sub via shfl ----
  f32x4 q = (f32x4)(0.0f);
#pragma unroll
  for (int r = 0; r < 8; ++r) {
    const int n = sub + 8 * r;
    const float av = __shfl(alpha, n);
    q[0] += av * px[r].x;
    q[1] += av * px[r].y;
    q[2] += av * px[r].z;
    q[3] += av * px[r].w;
  }
#pragma unroll
  for (int m = 1; m <= 4; m <<= 1) {
    q[0] += __shfl_xor(q[0], m);
    q[1] += __shfl_xor(q[1], m);
    q[2] += __shfl_xor(q[2], m);
    q[3] += __shfl_xor(q[3], m);
  }
  if (sub == 0)
    *(f32x4*)(pooled + ((size_t)b * T_ + t) * D_ + 4 * cg) = q;
}

__global__ __launch_bounds__(256) void temporal_kernel(
    const float* __restrict__ pooled,
    const short8* __restrict__ wfrag,     // fragments of tg_w1
    const float* __restrict__ b1,
    const float* __restrict__ w2,
    float* __restrict__ out) {
  __shared__ float xs[64][132];
  __shared__ float score_lds[64];
  __shared__ float tw_lds[64];
  __shared__ float pp[2][128];

  const int tid = threadIdx.x;
  const int b = blockIdx.x;

  const float* pb = pooled + (size_t)b * T_ * D_;
#pragma unroll
  for (int it = 0; it < 8; ++it) {
    int q = it * 256 + tid;
    int n = q >> 5;
    int c4 = (q & 31) << 2;
    float4 v = {0.f, 0.f, 0.f, 0.f};
    if (n < T_) v = *(const float4*)(pb + n * D_ + c4);
    *(float4*)(&xs[n][c4]) = v;   // rows 60..63 zero-padded
  }
  __syncthreads();

  const int l = tid & 63;
  const int w = tid >> 6;
  const int lg = l >> 4;
  const int lr = l & 15;

  float b1v[8], w2v[8];
#pragma unroll
  for (int nt = 0; nt < 8; ++nt) {
    b1v[nt] = b1[nt * 16 + lr];
    w2v[nt] = w2[nt * 16 + lr];
  }

  f32x4 acc[8];
#pragma unroll
  for (int nt = 0; nt < 8; ++nt) acc[nt] = (f32x4)(0.0f);

  const int row = 16 * w + lr;
#pragma unroll
  for (int kt = 0; kt < 4; ++kt) {
    const int k0 = kt * 32 + 8 * lg;
    float4 a0 = *(const float4*)(&xs[row][k0]);
    float4 a1 = *(const float4*)(&xs[row][k0 + 4]);
    short8 af;
    af[0] = (short)f2bf(a0.x); af[1] = (short)f2bf(a0.y);
    af[2] = (short)f2bf(a0.z); af[3] = (short)f2bf(a0.w);
    af[4] = (short)f2bf(a1.x); af[5] = (short)f2bf(a1.y);
    af[6] = (short)f2bf(a1.z); af[7] = (short)f2bf(a1.w);
#pragma unroll
    for (int nt = 0; nt < 8; ++nt) {
      short8 bf = wfrag[(kt * 8 + nt) * 64 + l];
      acc[nt] = __builtin_amdgcn_mfma_f32_16x16x32_bf16(af, bf, acc[nt], 0, 0, 0);
    }
  }

#pragma unroll
  for (int j = 0; j < 4; ++j) {
    float s = 0.f;
#pragma unroll
    for (int nt = 0; nt < 8; ++nt) {
      float h = acc[nt][j] + b1v[nt];
      s += tanh_fast(h) * w2v[nt];
    }
    s += __shfl_xor(s, 1);
    s += __shfl_xor(s, 2);
    s += __shfl_xor(s, 4);
    s += __shfl_xor(s, 8);
    if (lr == 0) score_lds[16 * w + 4 * lg + j] = s;
  }
  __syncthreads();

  // masked softmax over T=60 (no max shift; scores bounded)
  float p = (l < T_) ? __builtin_amdgcn_exp2f(score_lds[l] * 1.4426950408889634f) : 0.f;
  float sm = p;
  sm += __shfl_xor(sm, 32);
  sm += __shfl_xor(sm, 16);
  sm += __shfl_xor(sm, 8);
  sm += __shfl_xor(sm, 4);
  sm += __shfl_xor(sm, 2);
  sm += __shfl_xor(sm, 1);
  float tw = p / sm;
  if (w == 0) {
    tw_lds[l] = tw;
    if (l < T_) out[B_ * D_ + b * T_ + l] = tw;   // tw output
  }
  __syncthreads();

  const int c = tid & 127;
  const int hh = tid >> 7;
  float s = 0.f;
#pragma unroll
  for (int i = 0; i < 30; ++i) {
    int tt = 30 * hh + i;
    s += tw_lds[tt] * xs[tt][c];
  }
  pp[hh][c] = s;
  __syncthreads();
  if (tid < 128) out[(size_t)b * D_ + tid] = pp[0][tid] + pp[1][tid];
}

extern "C" void kernel_launch(void* const* d_in, const int* in_sizes, int n_in,
                              void* d_out, int out_size, void* d_ws, size_t ws_size,
                              hipStream_t stream) {
  const float* x     = (const float*)d_in[0];
  const float* sg_w1 = (const float*)d_in[1];
  const float* sg_b1 = (const float*)d_in[2];
  const float* sg_w2 = (const float*)d_in[3];
  const float* tg_w1 = (const float*)d_in[5];
  const float* tg_b1 = (const float*)d_in[6];
  const float* tg_w2 = (const float*)d_in[7];
  float* out = (float*)d_out;

  unsigned short* wfrag = (unsigned short*)d_ws;            // 2 * 2048 * 8 ushorts = 64 KB
  float* pooled = (float*)((char*)d_ws + 65536);            // B*T*D f32 = 7.86 MB

  prep_weights<<<16, 256, 0, stream>>>(sg_w1, tg_w1, wfrag);
  spatial_kernel<<<B_ * T_, 256, 0, stream>>>(
      x, (const short8*)wfrag, sg_b1, sg_w2, pooled);
  temporal_kernel<<<B_, 256, 0, stream>>>(
      pooled, (const short8*)(wfrag + 16384), tg_b1, tg_w2, out);
}

// Round 7
// 150.256 us; speedup vs baseline: 1.4091x; 1.0258x over previous
//
#include <hip/hip_runtime.h>

#define B_ 256
#define N_ 64
#define T_ 60
#define D_ 128
#define H_ 128

typedef __attribute__((ext_vector_type(8))) short short8;
typedef __attribute__((ext_vector_type(4))) float f32x4;

__device__ __forceinline__ unsigned short f2bf(float f) {
  unsigned int u = __builtin_bit_cast(unsigned int, f);
  u = u + 0x7FFFu + ((u >> 16) & 1u);   // round-to-nearest-even
  return (unsigned short)(u >> 16);
}

__device__ __forceinline__ float tanh_fast(float x) {
  float e = __builtin_amdgcn_exp2f(x * 2.885390081777927f);  // exp(2x)
  return 1.0f - 2.0f * __builtin_amdgcn_rcpf(e + 1.0f);
}

// Pack W (K=128 x N=128, row-major [k][n]) into bf16 B-fragment order:
// [kt(4)][nt(8)][lane(64)][elem(8)], value = W[kt*32 + 8*(l>>4) + i][nt*16 + (l&15)]
__global__ __launch_bounds__(256) void prep_weights(
    const float* __restrict__ sg_w1, const float* __restrict__ tg_w1,
    unsigned short* __restrict__ wfrag) {
  int tid = blockIdx.x * 256 + threadIdx.x;   // 0..4095
  if (tid >= 2 * 4 * 8 * 64) return;
  int l  = tid & 63;
  int nt = (tid >> 6) & 7;
  int kt = (tid >> 9) & 3;
  int m  = tid >> 11;
  const float* W = m ? tg_w1 : sg_w1;
  int n  = nt * 16 + (l & 15);
  int k0 = kt * 32 + 8 * (l >> 4);
  unsigned short* dst = wfrag + (size_t)tid * 8;
#pragma unroll
  for (int i = 0; i < 8; ++i) dst[i] = f2bf(W[(k0 + i) * H_ + n]);
}

// Block = (b, pair of timesteps). Each wave-load covers one node's 1KB
// contiguous span x[b,n,t0:t0+2,:] -> 2x larger DRAM chunks than 1-t blocks.
// 8 waves: (t, row-half, col-half). Pool from staging registers.
__global__ __launch_bounds__(512, 4) void spatial_kernel(
    const float* __restrict__ x,
    const short8* __restrict__ wfrag,     // [4][8][64] fragments of sg_w1
    const float* __restrict__ b1,
    const float* __restrict__ w2,
    float* __restrict__ pooled) {
  __shared__ __align__(16) char xt16[2 * 17408];   // bf16 tiles, 272B row stride
  __shared__ float gpart[2][2][64];
  __shared__ float alph[2][64];
  __shared__ f32x4 pp[8][64];

  const int tid = threadIdx.x;
  const int bid = blockIdx.x;
  const int b  = bid / (T_ / 2);
  const int tc = bid - b * (T_ / 2);
  const int t0 = 2 * tc;

  const int w = tid >> 6;     // wave 0..7
  const int l = tid & 63;

  // ---- stage: 8 loads; load j = full 1KB span of node n=8j+w ----
  const float* xb = x + (size_t)b * (N_ * T_ * D_) + (size_t)t0 * D_;
  float4 px[8];
#pragma unroll
  for (int j = 0; j < 8; ++j)
    px[j] = *(const float4*)(xb + (size_t)(8 * j + w) * (T_ * D_) + 4 * l);

  // lane's data: t = l>>5, d4 = l&31, node = 8j+w
  const int lt  = l >> 5;
  const int d4  = l & 31;
#pragma unroll
  for (int j = 0; j < 8; ++j) {
    unsigned lo = ((unsigned)f2bf(px[j].y) << 16) | f2bf(px[j].x);
    unsigned hi = ((unsigned)f2bf(px[j].w) << 16) | f2bf(px[j].z);
    *(uint2*)(xt16 + lt * 17408 + (8 * j + w) * 272 + d4 * 8) = make_uint2(lo, hi);
  }
  __syncthreads();

  const int lg = l >> 4;
  const int lr = l & 15;
  const int tw = w >> 2;        // timestep this wave computes
  const int wr = (w >> 1) & 1;  // row half: nodes [32*wr, 32*wr+32)
  const int wc = w & 1;         // col half: H cols [64*wc, 64*wc+64)

  float b1v[4], w2v[4];
#pragma unroll
  for (int ntl = 0; ntl < 4; ++ntl) {
    b1v[ntl] = b1[wc * 64 + ntl * 16 + lr];
    w2v[ntl] = w2[wc * 64 + ntl * 16 + lr];
  }

  // ---- MFMA: h = x(tw) @ W1 for (row-half x col-half) ----
  f32x4 acc[2][4];
#pragma unroll
  for (int mt = 0; mt < 2; ++mt)
#pragma unroll
    for (int ntl = 0; ntl < 4; ++ntl) acc[mt][ntl] = (f32x4)(0.0f);

#pragma unroll
  for (int kt = 0; kt < 4; ++kt) {
#pragma unroll
    for (int mt = 0; mt < 2; ++mt) {
      const int row = 32 * wr + 16 * mt + lr;
      short8 af = *(const short8*)(xt16 + tw * 17408 + row * 272 + kt * 64 + lg * 16);
#pragma unroll
      for (int ntl = 0; ntl < 4; ++ntl) {
        short8 bf = wfrag[(kt * 8 + wc * 4 + ntl) * 64 + l];   // streamed from L2
        acc[mt][ntl] = __builtin_amdgcn_mfma_f32_16x16x32_bf16(af, bf, acc[mt][ntl], 0, 0, 0);
      }
    }
  }

  // ---- gate partials; node = 32wr + 16mt + 4lg + j ----
#pragma unroll
  for (int mt = 0; mt < 2; ++mt) {
#pragma unroll
    for (int j = 0; j < 4; ++j) {
      float s = 0.f;
#pragma unroll
      for (int ntl = 0; ntl < 4; ++ntl) {
        float h = acc[mt][ntl][j] + b1v[ntl];
        s += tanh_fast(h) * w2v[ntl];
      }
      s += __shfl_xor(s, 1);
      s += __shfl_xor(s, 2);
      s += __shfl_xor(s, 4);
      s += __shfl_xor(s, 8);
      if (lr == 0) gpart[tw][wc][32 * wr + 16 * mt + 4 * lg + j] = s;
    }
  }
  __syncthreads();

  // ---- softmax per timestep (waves 0 and 4), no max shift ----
  if ((w & 3) == 0) {
    float g = gpart[tw][0][l] + gpart[tw][1][l];
    float p = __builtin_amdgcn_exp2f(g * 1.4426950408889634f);
    float sm = p;
    sm += __shfl_xor(sm, 32);
    sm += __shfl_xor(sm, 16);
    sm += __shfl_xor(sm, 8);
    sm += __shfl_xor(sm, 4);
    sm += __shfl_xor(sm, 2);
    sm += __shfl_xor(sm, 1);
    alph[tw][l] = p * __builtin_amdgcn_rcpf(sm);
  }
  __syncthreads();

  // ---- pool from staging registers; alpha via LDS broadcast ----
  f32x4 q = (f32x4)(0.0f);
#pragma unroll
  for (int j = 0; j < 8; ++j) {
    const float av = alph[lt][8 * j + w];
    q[0] += av * px[j].x;
    q[1] += av * px[j].y;
    q[2] += av * px[j].z;
    q[3] += av * px[j].w;
  }
  pp[w][l] = q;
  __syncthreads();

  // ---- final cross-wave reduce + store (wave 0) ----
  if (w == 0) {
    f32x4 s4 = pp[0][l];
#pragma unroll
    for (int w2i = 1; w2i < 8; ++w2i) s4 += pp[w2i][l];
    *(f32x4*)(pooled + ((size_t)b * T_ + t0 + lt) * D_ + 4 * d4) = s4;
  }
}

__global__ __launch_bounds__(256) void temporal_kernel(
    const float* __restrict__ pooled,
    const short8* __restrict__ wfrag,     // fragments of tg_w1
    const float* __restrict__ b1,
    const float* __restrict__ w2,
    float* __restrict__ out) {
  __shared__ float xs[64][132];
  __shared__ float score_lds[64];
  __shared__ float tw_lds[64];
  __shared__ float pp[2][128];

  const int tid = threadIdx.x;
  const int b = blockIdx.x;

  const float* pb = pooled + (size_t)b * T_ * D_;
#pragma unroll
  for (int it = 0; it < 8; ++it) {
    int q = it * 256 + tid;
    int n = q >> 5;
    int c4 = (q & 31) << 2;
    float4 v = {0.f, 0.f, 0.f, 0.f};
    if (n < T_) v = *(const float4*)(pb + n * D_ + c4);
    *(float4*)(&xs[n][c4]) = v;   // rows 60..63 zero-padded
  }
  __syncthreads();

  const int l = tid & 63;
  const int w = tid >> 6;
  const int lg = l >> 4;
  const int lr = l & 15;

  float b1v[8], w2v[8];
#pragma unroll
  for (int nt = 0; nt < 8; ++nt) {
    b1v[nt] = b1[nt * 16 + lr];
    w2v[nt] = w2[nt * 16 + lr];
  }

  f32x4 acc[8];
#pragma unroll
  for (int nt = 0; nt < 8; ++nt) acc[nt] = (f32x4)(0.0f);

  const int row = 16 * w + lr;
#pragma unroll
  for (int kt = 0; kt < 4; ++kt) {
    const int k0 = kt * 32 + 8 * lg;
    float4 a0 = *(const float4*)(&xs[row][k0]);
    float4 a1 = *(const float4*)(&xs[row][k0 + 4]);
    short8 af;
    af[0] = (short)f2bf(a0.x); af[1] = (short)f2bf(a0.y);
    af[2] = (short)f2bf(a0.z); af[3] = (short)f2bf(a0.w);
    af[4] = (short)f2bf(a1.x); af[5] = (short)f2bf(a1.y);
    af[6] = (short)f2bf(a1.z); af[7] = (short)f2bf(a1.w);
#pragma unroll
    for (int nt = 0; nt < 8; ++nt) {
      short8 bf = wfrag[(kt * 8 + nt) * 64 + l];
      acc[nt] = __builtin_amdgcn_mfma_f32_16x16x32_bf16(af, bf, acc[nt], 0, 0, 0);
    }
  }

#pragma unroll
  for (int j = 0; j < 4; ++j) {
    float s = 0.f;
#pragma unroll
    for (int nt = 0; nt < 8; ++nt) {
      float h = acc[nt][j] + b1v[nt];
      s += tanh_fast(h) * w2v[nt];
    }
    s += __shfl_xor(s, 1);
    s += __shfl_xor(s, 2);
    s += __shfl_xor(s, 4);
    s += __shfl_xor(s, 8);
    if (lr == 0) score_lds[16 * w + 4 * lg + j] = s;
  }
  __syncthreads();

  // masked softmax over T=60 (no max shift; scores bounded)
  float p = (l < T_) ? __builtin_amdgcn_exp2f(score_lds[l] * 1.4426950408889634f) : 0.f;
  float sm = p;
  sm += __shfl_xor(sm, 32);
  sm += __shfl_xor(sm, 16);
  sm += __shfl_xor(sm, 8);
  sm += __shfl_xor(sm, 4);
  sm += __shfl_xor(sm, 2);
  sm += __shfl_xor(sm, 1);
  float tw = p / sm;
  if (w == 0) {
    tw_lds[l] = tw;
    if (l < T_) out[B_ * D_ + b * T_ + l] = tw;   // tw output
  }
  __syncthreads();

  const int c = tid & 127;
  const int hh = tid >> 7;
  float s = 0.f;
#pragma unroll
  for (int i = 0; i < 30; ++i) {
    int tt = 30 * hh + i;
    s += tw_lds[tt] * xs[tt][c];
  }
  pp[hh][c] = s;
  __syncthreads();
  if (tid < 128) out[(size_t)b * D_ + tid] = pp[0][tid] + pp[1][tid];
}

extern "C" void kernel_launch(void* const* d_in, const int* in_sizes, int n_in,
                              void* d_out, int out_size, void* d_ws, size_t ws_size,
                              hipStream_t stream) {
  const float* x     = (const float*)d_in[0];
  const float* sg_w1 = (const float*)d_in[1];
  const float* sg_b1 = (const float*)d_in[2];
  const float* sg_w2 = (const float*)d_in[3];
  const float* tg_w1 = (const float*)d_in[5];
  const float* tg_b1 = (const float*)d_in[6];
  const float* tg_w2 = (const float*)d_in[7];
  float* out = (float*)d_out;

  unsigned short* wfrag = (unsigned short*)d_ws;            // 2 * 2048 * 8 ushorts = 64 KB
  float* pooled = (float*)((char*)d_ws + 65536);            // B*T*D f32 = 7.86 MB

  prep_weights<<<16, 256, 0, stream>>>(sg_w1, tg_w1, wfrag);
  spatial_kernel<<<B_ * (T_ / 2), 512, 0, stream>>>(
      x, (const short8*)wfrag, sg_b1, sg_w2, pooled);
  temporal_kernel<<<B_, 256, 0, stream>>>(
      pooled, (const short8*)(wfrag + 16384), tg_b1, tg_w2, out);
}

// Round 8
// 144.691 us; speedup vs baseline: 1.4633x; 1.0385x over previous
//
#include <hip/hip_runtime.h>

#define B_ 256
#define N_ 64
#define T_ 60
#define D_ 128
#define H_ 128

typedef __attribute__((ext_vector_type(8))) short short8;
typedef __attribute__((ext_vector_type(4))) float f32x4;

__device__ __forceinline__ unsigned short f2bf(float f) {
  unsigned int u = __builtin_bit_cast(unsigned int, f);
  u = u + 0x7FFFu + ((u >> 16) & 1u);   // round-to-nearest-even
  return (unsigned short)(u >> 16);
}

__device__ __forceinline__ float tanh_fast(float x) {
  float e = __builtin_amdgcn_exp2f(x * 2.885390081777927f);  // exp(2x)
  return 1.0f - 2.0f * __builtin_amdgcn_rcpf(e + 1.0f);
}

// LDS-only barrier: does not drain vmcnt, so in-flight global prefetch
// loads survive it.
__device__ __forceinline__ void lds_barrier() {
  asm volatile("s_waitcnt lgkmcnt(0)" ::: "memory");
  __builtin_amdgcn_s_barrier();
  asm volatile("" ::: "memory");
}

// Pack W (K=128 x N=128, row-major [k][n]) into bf16 B-fragment order:
// [kt(4)][nt(8)][lane(64)][elem(8)], value = W[kt*32 + 8*(l>>4) + i][nt*16 + (l&15)]
__global__ __launch_bounds__(256) void prep_weights(
    const float* __restrict__ sg_w1, const float* __restrict__ tg_w1,
    unsigned short* __restrict__ wfrag) {
  int tid = blockIdx.x * 256 + threadIdx.x;   // 0..4095
  if (tid >= 2 * 4 * 8 * 64) return;
  int l  = tid & 63;
  int nt = (tid >> 6) & 7;
  int kt = (tid >> 9) & 3;
  int m  = tid >> 11;
  const float* W = m ? tg_w1 : sg_w1;
  int n  = nt * 16 + (l & 15);
  int k0 = kt * 32 + 8 * (l >> 4);
  unsigned short* dst = wfrag + (size_t)tid * 8;
#pragma unroll
  for (int i = 0; i < 8; ++i) dst[i] = f2bf(W[(k0 + i) * H_ + n]);
}

// Block = (b, node-half). Streams x[b, nh*32 .. nh*32+31, :, :] as 32
// CONTIGUOUS 30KB slabs (block footprint = one linear ~1MB sweep).
// Per slab: gate MLP over rows t (M=64 pad), e=exp(gate) (bounded, no max),
// online-accumulate acc[t][d] += e*x and den[t] += e in REGISTERS.
// W fragments live in LDS (keeps vmcnt queue = px prefetch only).
__global__ __launch_bounds__(256, 2) void spatial_kernel(
    const float* __restrict__ x,
    const unsigned short* __restrict__ wfrag_g,  // sg_w1 fragments
    const float* __restrict__ b1,
    const float* __restrict__ w2,
    float* __restrict__ acc_p,    // [512][64][128]
    float* __restrict__ den_p) {  // [512][64]
  __shared__ __align__(16) char tile[64 * 272];   // bf16 slab, 272B row stride
  __shared__ __align__(16) char wlds[32768];      // 32 B-fragments
  __shared__ float gpart[2][64];

  const int tid = threadIdx.x;
  const int bid = blockIdx.x;
  const int b  = bid >> 1;
  const int nh = bid & 1;

  const int sub = tid >> 5;    // 0..7   (row group)
  const int cg  = tid & 31;    // 0..31  (col group of 4 floats)

  const float* xb = x + (size_t)b * (N_ * T_ * D_) + (size_t)(nh * 32) * (T_ * D_);

  // per-thread row offsets within a slab (t clamped to 59: rows 60..63 are
  // padding whose outputs are never read)
  int roff[8];
#pragma unroll
  for (int r = 0; r < 8; ++r) {
    int t = 8 * r + sub;
    roff[r] = (t > 59 ? 59 : t) * D_ + 4 * cg;
  }

  const int l  = tid & 63;
  const int w  = tid >> 6;
  const int lg = l >> 4;
  const int lr = l & 15;
  const int wr = w >> 1;   // t-half  [32*wr, 32*wr+32)
  const int wc = w & 1;    // h-half  [64*wc, 64*wc+64)

  float b1v[4], w2v[4];
#pragma unroll
  for (int ntl = 0; ntl < 4; ++ntl) {
    b1v[ntl] = b1[wc * 64 + ntl * 16 + lr];
    w2v[ntl] = w2[wc * 64 + ntl * 16 + lr];
  }

  // ---- prologue: W-fragments -> LDS; issue slab-0 loads ----
  float4 wtmp[8];
#pragma unroll
  for (int i = 0; i < 8; ++i)
    wtmp[i] = *(const float4*)(wfrag_g + (size_t)(tid + 256 * i) * 8);

  float4 pxA[8], pxB[8];
#pragma unroll
  for (int r = 0; r < 8; ++r) pxA[r] = *(const float4*)(xb + roff[r]);

#pragma unroll
  for (int i = 0; i < 8; ++i)
    *(float4*)(wlds + (size_t)(tid + 256 * i) * 16) = wtmp[i];
  lds_barrier();

  f32x4 accr[8];
  float denr[8];
#pragma unroll
  for (int r = 0; r < 8; ++r) { accr[r] = (f32x4)(0.0f); denr[r] = 0.0f; }

#define SLAB_BODY(CUR, NXT, S)                                                  \
  {                                                                             \
    /* issue next slab's loads (fly under this slab's compute) */               \
    if ((S) < 31) {                                                             \
      const float* nsb = xb + (size_t)((S) + 1) * (T_ * D_);                    \
      _Pragma("unroll")                                                         \
      for (int r = 0; r < 8; ++r) NXT[r] = *(const float4*)(nsb + roff[r]);     \
    }                                                                           \
    /* A: convert CUR -> bf16 tile */                                           \
    _Pragma("unroll")                                                           \
    for (int r = 0; r < 8; ++r) {                                               \
      const int t = 8 * r + sub;                                                \
      unsigned lo = ((unsigned)f2bf(CUR[r].y) << 16) | f2bf(CUR[r].x);          \
      unsigned hi = ((unsigned)f2bf(CUR[r].w) << 16) | f2bf(CUR[r].z);          \
      *(uint2*)(tile + t * 272 + cg * 8) = make_uint2(lo, hi);                  \
    }                                                                           \
    lds_barrier();                                                              \
    /* B: MFMA h = slab @ W1 (rows = t), gate partials */                       \
    {                                                                           \
      f32x4 macc[2][4];                                                         \
      _Pragma("unroll")                                                         \
      for (int mt = 0; mt < 2; ++mt)                                            \
        _Pragma("unroll")                                                       \
        for (int ntl = 0; ntl < 4; ++ntl) macc[mt][ntl] = (f32x4)(0.0f);        \
      _Pragma("unroll")                                                         \
      for (int kt = 0; kt < 4; ++kt) {                                          \
        _Pragma("unroll")                                                       \
        for (int mt = 0; mt < 2; ++mt) {                                        \
          const int row = 32 * wr + 16 * mt + lr;                               \
          short8 af = *(const short8*)(tile + row * 272 + kt * 64 + lg * 16);   \
          _Pragma("unroll")                                                     \
          for (int ntl = 0; ntl < 4; ++ntl) {                                   \
            short8 bf = *(const short8*)(                                       \
                wlds + ((kt * 8 + wc * 4 + ntl) * 64 + l) * 16);                \
            macc[mt][ntl] = __builtin_amdgcn_mfma_f32_16x16x32_bf16(            \
                af, bf, macc[mt][ntl], 0, 0, 0);                                \
          }                                                                     \
        }                                                                       \
      }                                                                         \
      _Pragma("unroll")                                                         \
      for (int mt = 0; mt < 2; ++mt) {                                          \
        _Pragma("unroll")                                                       \
        for (int j = 0; j < 4; ++j) {                                           \
          float sg = 0.f;                                                       \
          _Pragma("unroll")                                                     \
          for (int ntl = 0; ntl < 4; ++ntl) {                                   \
            float h = macc[mt][ntl][j] + b1v[ntl];                              \
            sg += tanh_fast(h) * w2v[ntl];                                      \
          }                                                                     \
          sg += __shfl_xor(sg, 1);                                              \
          sg += __shfl_xor(sg, 2);                                              \
          sg += __shfl_xor(sg, 4);                                              \
          sg += __shfl_xor(sg, 8);                                              \
          if (lr == 0) gpart[wc][32 * wr + 16 * mt + 4 * lg + j] = sg;          \
        }                                                                       \
      }                                                                         \
    }                                                                           \
    lds_barrier();                                                              \
    /* D: e = exp(gate), online accumulate from CUR registers */                \
    _Pragma("unroll")                                                           \
    for (int r = 0; r < 8; ++r) {                                               \
      const int t = 8 * r + sub;                                                \
      float g = gpart[0][t] + gpart[1][t];                                      \
      float e = __builtin_amdgcn_exp2f(g * 1.4426950408889634f);                \
      accr[r][0] += e * CUR[r].x;                                               \
      accr[r][1] += e * CUR[r].y;                                               \
      accr[r][2] += e * CUR[r].z;                                               \
      accr[r][3] += e * CUR[r].w;                                               \
      denr[r] += e;                                                             \
    }                                                                           \
    lds_barrier();                                                              \
  }

  for (int sp = 0; sp < 16; ++sp) {
    const int s0 = 2 * sp;
    SLAB_BODY(pxA, pxB, s0);
    SLAB_BODY(pxB, pxA, s0 + 1);
  }
#undef SLAB_BODY

  // ---- epilogue: write partial acc / den ----
#pragma unroll
  for (int r = 0; r < 8; ++r) {
    const int t = 8 * r + sub;
    *(f32x4*)(acc_p + ((size_t)bid * 64 + t) * D_ + 4 * cg) = accr[r];
  }
  if (cg == 0) {
#pragma unroll
    for (int r = 0; r < 8; ++r) den_p[bid * 64 + 8 * r + sub] = denr[r];
  }
}

__global__ __launch_bounds__(256) void temporal_kernel(
    const float* __restrict__ acc_p,
    const float* __restrict__ den_p,
    const short8* __restrict__ wfrag,     // fragments of tg_w1
    const float* __restrict__ b1,
    const float* __restrict__ w2,
    float* __restrict__ out) {
  __shared__ float xs[64][132];
  __shared__ float score_lds[64];
  __shared__ float tw_lds[64];
  __shared__ float pp[2][128];

  const int tid = threadIdx.x;
  const int b = blockIdx.x;

  // combine the two node-half partials into pooled rows on load
  const float* a0 = acc_p + (size_t)(2 * b) * (64 * D_);
  const float* a1 = a0 + 64 * D_;
  const float* d0 = den_p + (2 * b) * 64;
  const float* d1 = d0 + 64;
#pragma unroll
  for (int it = 0; it < 8; ++it) {
    int q = it * 256 + tid;
    int n = q >> 5;
    int c4 = (q & 31) << 2;
    float4 v = {0.f, 0.f, 0.f, 0.f};
    if (n < T_) {
      float4 v0 = *(const float4*)(a0 + n * D_ + c4);
      float4 v1 = *(const float4*)(a1 + n * D_ + c4);
      float inv = __builtin_amdgcn_rcpf(d0[n] + d1[n]);
      v.x = (v0.x + v1.x) * inv;
      v.y = (v0.y + v1.y) * inv;
      v.z = (v0.z + v1.z) * inv;
      v.w = (v0.w + v1.w) * inv;
    }
    *(float4*)(&xs[n][c4]) = v;   // rows 60..63 zero-padded
  }
  __syncthreads();

  const int l = tid & 63;
  const int w = tid >> 6;
  const int lg = l >> 4;
  const int lr = l & 15;

  float b1v[8], w2v[8];
#pragma unroll
  for (int nt = 0; nt < 8; ++nt) {
    b1v[nt] = b1[nt * 16 + lr];
    w2v[nt] = w2[nt * 16 + lr];
  }

  f32x4 acc[8];
#pragma unroll
  for (int nt = 0; nt < 8; ++nt) acc[nt] = (f32x4)(0.0f);

  const int row = 16 * w + lr;
#pragma unroll
  for (int kt = 0; kt < 4; ++kt) {
    const int k0 = kt * 32 + 8 * lg;
    float4 a0v = *(const float4*)(&xs[row][k0]);
    float4 a1v = *(const float4*)(&xs[row][k0 + 4]);
    short8 af;
    af[0] = (short)f2bf(a0v.x); af[1] = (short)f2bf(a0v.y);
    af[2] = (short)f2bf(a0v.z); af[3] = (short)f2bf(a0v.w);
    af[4] = (short)f2bf(a1v.x); af[5] = (short)f2bf(a1v.y);
    af[6] = (short)f2bf(a1v.z); af[7] = (short)f2bf(a1v.w);
#pragma unroll
    for (int nt = 0; nt < 8; ++nt) {
      short8 bf = wfrag[(kt * 8 + nt) * 64 + l];
      acc[nt] = __builtin_amdgcn_mfma_f32_16x16x32_bf16(af, bf, acc[nt], 0, 0, 0);
    }
  }

#pragma unroll
  for (int j = 0; j < 4; ++j) {
    float s = 0.f;
#pragma unroll
    for (int nt = 0; nt < 8; ++nt) {
      float h = acc[nt][j] + b1v[nt];
      s += tanh_fast(h) * w2v[nt];
    }
    s += __shfl_xor(s, 1);
    s += __shfl_xor(s, 2);
    s += __shfl_xor(s, 4);
    s += __shfl_xor(s, 8);
    if (lr == 0) score_lds[16 * w + 4 * lg + j] = s;
  }
  __syncthreads();

  // masked softmax over T=60 (no max shift; scores bounded)
  float p = (l < T_) ? __builtin_amdgcn_exp2f(score_lds[l] * 1.4426950408889634f) : 0.f;
  float sm = p;
  sm += __shfl_xor(sm, 32);
  sm += __shfl_xor(sm, 16);
  sm += __shfl_xor(sm, 8);
  sm += __shfl_xor(sm, 4);
  sm += __shfl_xor(sm, 2);
  sm += __shfl_xor(sm, 1);
  float tw = p / sm;
  if (w == 0) {
    tw_lds[l] = tw;
    if (l < T_) out[B_ * D_ + b * T_ + l] = tw;   // tw output
  }
  __syncthreads();

  const int c = tid & 127;
  const int hh = tid >> 7;
  float s = 0.f;
#pragma unroll
  for (int i = 0; i < 30; ++i) {
    int tt = 30 * hh + i;
    s += tw_lds[tt] * xs[tt][c];
  }
  pp[hh][c] = s;
  __syncthreads();
  if (tid < 128) out[(size_t)b * D_ + tid] = pp[0][tid] + pp[1][tid];
}

extern "C" void kernel_launch(void* const* d_in, const int* in_sizes, int n_in,
                              void* d_out, int out_size, void* d_ws, size_t ws_size,
                              hipStream_t stream) {
  const float* x     = (const float*)d_in[0];
  const float* sg_w1 = (const float*)d_in[1];
  const float* sg_b1 = (const float*)d_in[2];
  const float* sg_w2 = (const float*)d_in[3];
  const float* tg_w1 = (const float*)d_in[5];
  const float* tg_b1 = (const float*)d_in[6];
  const float* tg_w2 = (const float*)d_in[7];
  float* out = (float*)d_out;

  unsigned short* wfrag = (unsigned short*)d_ws;            // 64 KB (sg @0, tg @16384)
  float* acc_p = (float*)((char*)d_ws + 65536);             // 512*64*128 f32 = 16.8 MB
  float* den_p = (float*)((char*)d_ws + 65536 + 16777216);  // 512*64 f32

  prep_weights<<<16, 256, 0, stream>>>(sg_w1, tg_w1, wfrag);
  spatial_kernel<<<B_ * 2, 256, 0, stream>>>(
      x, wfrag, sg_b1, sg_w2, acc_p, den_p);
  temporal_kernel<<<B_, 256, 0, stream>>>(
      acc_p, den_p, (const short8*)(wfrag + 16384), tg_b1, tg_w2, out);
}